// Round 5
// baseline (697.571 us; speedup 1.0000x reference)
//
#include <hip/hip_runtime.h>
#include <hip/hip_bf16.h>
#include <math.h>

#define ALPHA 0.01f

typedef __bf16 bf16x8 __attribute__((ext_vector_type(8)));
typedef float  floatx4 __attribute__((ext_vector_type(4)));

static __device__ __forceinline__ unsigned short f2bf_bits(float f) {
    return __builtin_bit_cast(unsigned short, (__bf16)f);   // RNE
}
static __device__ __forceinline__ float bf2f(unsigned short u) {
    return __builtin_bit_cast(float, (unsigned)u << 16);    // exact
}

// 16-lane (DPP row) reductions — pure VALU, no LDS traffic.
template <int CTRL>
static __device__ __forceinline__ float dppmov(float x) {
    int r = __builtin_amdgcn_update_dpp(0, __builtin_bit_cast(int, x), CTRL, 0xf, 0xf, false);
    return __builtin_bit_cast(float, r);
}
static __device__ __forceinline__ float red16min(float x) {
    x = fminf(x, dppmov<0x121>(x)); x = fminf(x, dppmov<0x122>(x));
    x = fminf(x, dppmov<0x124>(x)); x = fminf(x, dppmov<0x128>(x));
    return x;
}
static __device__ __forceinline__ float red16max(float x) {
    x = fmaxf(x, dppmov<0x121>(x)); x = fmaxf(x, dppmov<0x122>(x));
    x = fmaxf(x, dppmov<0x124>(x)); x = fmaxf(x, dppmov<0x128>(x));
    return x;
}
static __device__ __forceinline__ float red16sum(float x) {
    x += dppmov<0x121>(x); x += dppmov<0x122>(x);
    x += dppmov<0x124>(x); x += dppmov<0x128>(x);
    return x;
}

// ---------------------------------------------------------------------------
// Barrier-free MFMA layer: Y(bf16) = leaky_relu(X @ W^T + b) + per-row
// histogram entropy (bins = DOUT) summed into *Hacc.
//
// NO __syncthreads anywhere. W lives in GLOBAL memory in fragment-major
// order (16B slot s = (kt*CTN+ct)*64 + lane) -> each B-frag read is one
// fully-coalesced 1 KB global_load_dwordx4 that hits per-XCD L2 (W <= 400KB).
// A-frags load direct from global (A-layout = 16 contiguous bytes of a row;
// fp32->bf16 packed in-register for L1). Latency hiding = free-running
// vmcnt pipelining across the unrolled K-loop + multi-wave occupancy.
//
// Block = 256 thr (4 waves); wave owns AF*16 rows (AF A-frags), block =
// AF*64 rows. Entropy runs register-resident per quad (4 rows in parallel,
// DPP 16-lane reductions); histogram = per-(wave,quad) u32 LDS counts
// (stride DOUT+1 words to decorrelate banks across the 16 arrays).
// ---------------------------------------------------------------------------
template <int DIN, int DOUT, bool XF32, int AF>
__global__ __launch_bounds__(256, 2) void layer_mfma(
    const void* __restrict__ Xin, const unsigned short* __restrict__ Wf,
    const float* __restrict__ bias, unsigned short* __restrict__ Y,
    float* __restrict__ Hacc)
{
    constexpr int CTN    = DOUT / 16;
    constexpr int KTFULL = DIN / 32;
    constexpr int TAIL   = DIN % 32;
    constexpr float LOGB = (DOUT == 256) ? 5.54517744f
                         : (DOUT == 128) ? 4.85203026f : 3.46573590f;
    static_assert(DOUT % 32 == 0 && DOUT <= 256, "DOUT");
    static_assert(XF32 || TAIL == 0, "bf16 input requires DIN%32==0");

    __shared__ unsigned int counts[16][DOUT + 1];

    const int t      = threadIdx.x;
    const int lane   = t & 63;
    const int lane16 = lane & 15;
    const int q      = lane >> 4;
    const int w      = t >> 6;
    const int row0   = blockIdx.x * (AF * 64);
    const int wrow0  = row0 + w * (AF * 16) + lane16;   // + rt*16 per frag

    floatx4 acc[AF][CTN];
    #pragma unroll
    for (int rt = 0; rt < AF; rt++)
        #pragma unroll
        for (int ct = 0; ct < CTN; ct++) acc[rt][ct] = (floatx4)(0.0f);

    // ---- one 32-wide k-tile: direct-global A frags + L2-hit B frags + MFMA
    auto ktile = [&](int kt, bool tail) {
        const int kg = kt * 32;
        bf16x8 a[AF];
        #pragma unroll
        for (int rt = 0; rt < AF; rt++) {
            if constexpr (XF32) {
                const float* p = (const float*)Xin
                               + (size_t)(wrow0 + rt * 16) * DIN + kg + q * 8;
                float4 v0 = make_float4(0.f, 0.f, 0.f, 0.f), v1 = v0;
                if (!tail || q * 8 + 8 <= TAIL) {
                    v0 = *(const float4*)p;
                    v1 = *(const float4*)(p + 4);
                }
                uint4 pk;
                pk.x = (unsigned)f2bf_bits(v0.x) | ((unsigned)f2bf_bits(v0.y) << 16);
                pk.y = (unsigned)f2bf_bits(v0.z) | ((unsigned)f2bf_bits(v0.w) << 16);
                pk.z = (unsigned)f2bf_bits(v1.x) | ((unsigned)f2bf_bits(v1.y) << 16);
                pk.w = (unsigned)f2bf_bits(v1.z) | ((unsigned)f2bf_bits(v1.w) << 16);
                a[rt] = __builtin_bit_cast(bf16x8, pk);
            } else {
                a[rt] = *(const bf16x8*)((const unsigned short*)Xin
                        + (size_t)(wrow0 + rt * 16) * DIN + kg + q * 8);
            }
        }
        const unsigned short* wb = Wf + ((size_t)kt * CTN * 64 + lane) * 8;
        #pragma unroll
        for (int ct = 0; ct < CTN; ct++) {
            bf16x8 bw = *(const bf16x8*)(wb + ct * 512);
            #pragma unroll
            for (int rt = 0; rt < AF; rt++)
                acc[rt][ct] = __builtin_amdgcn_mfma_f32_16x16x32_bf16(a[rt], bw, acc[rt][ct], 0, 0, 0);
        }
    };

    #pragma unroll 4
    for (int kt = 0; kt < KTFULL; kt++) ktile(kt, false);
    if constexpr (TAIL > 0) ktile(KTFULL, true);

    // ---- epilogue: bias + leaky_relu in registers; direct bf16 stores
    float biasr[CTN];
    #pragma unroll
    for (int ct = 0; ct < CTN; ct++) biasr[ct] = bias[ct * 16 + lane16];

    #pragma unroll
    for (int rt = 0; rt < AF; rt++)
        #pragma unroll
        for (int ct = 0; ct < CTN; ct++) {
            #pragma unroll
            for (int reg = 0; reg < 4; reg++) {
                float v = acc[rt][ct][reg] + biasr[ct];
                v = v > 0.0f ? v : ALPHA * v;
                acc[rt][ct][reg] = v;
                Y[(size_t)(row0 + w * (AF * 16) + rt * 16 + q * 4 + reg) * DOUT
                  + ct * 16 + lane16] = f2bf_bits(v);
            }
        }

    // ---- entropy: quad q processes rows rt*16 + q*4 + reg
    unsigned int* cc = counts[w * 4 + q];
    float Hq = 0.0f;
    #pragma unroll
    for (int rt = 0; rt < AF; rt++) {
        #pragma unroll
        for (int reg = 0; reg < 4; reg++) {
            float mn = acc[rt][0][reg], mx = mn;
            #pragma unroll
            for (int ct = 1; ct < CTN; ct++) {
                mn = fminf(mn, acc[rt][ct][reg]);
                mx = fmaxf(mx, acc[rt][ct][reg]);
            }
            mn = red16min(mn);
            mx = red16max(mx);
            float wdt = mx - mn;
            float scale = (float)DOUT / (wdt > 0.0f ? wdt : 1.0f);

            #pragma unroll
            for (int i = 0; i < DOUT / 16; i++) cc[lane16 + 16 * i] = 0u;
            // DS ops from one wave complete in order: zeros -> atomics -> reads

            #pragma unroll
            for (int ct = 0; ct < CTN; ct++) {
                int b = (int)((acc[rt][ct][reg] - mn) * scale);
                b = b < (DOUT - 1) ? b : (DOUT - 1);
                atomicAdd(&cc[b], 1u);
            }

            float s = 0.0f;
            #pragma unroll
            for (int i = 0; i < DOUT / 16; i++) {
                int cnt = (int)cc[lane16 + 16 * i];
                if (cnt > 0) { float p = (float)cnt * (1.0f / (float)DOUT); s += p * __logf(p); }
            }
            s = red16sum(s);
            Hq += LOGB - s;
        }
    }
    Hq += __shfl_xor(Hq, 16, 64);
    Hq += __shfl_xor(Hq, 32, 64);
    if (lane == 0) atomicAdd(Hacc, Hq);
}

// ---------------------------------------------------------------------------
// fp32 W1..W5 -> bf16 fragment-major slots, concatenated into ws.
// Slot s holds W[ct*16 + (lane&15)][kt*32 + (lane>>4)*8 .. +8), zero-padded
// past DIN, where within a layer s_local = (kt*CTN + ct)*64 + lane.
// ---------------------------------------------------------------------------
__global__ void convert_wfrag(const float* __restrict__ W1, const float* __restrict__ W2,
                              const float* __restrict__ W3, const float* __restrict__ W4,
                              const float* __restrict__ W5, unsigned short* __restrict__ out)
{
    // slots: L1 25*16*64=25600 | L2 8*8*64=4096 | L3 4*8*64=2048 | L4 2048 | L5 4*2*64=512
    int s = blockIdx.x * 256 + threadIdx.x;
    if (s >= 34304) return;
    const float* W; int DIN, CTN, sl;
    if      (s < 25600) { W = W1; DIN = 784; CTN = 16; sl = s;         }
    else if (s < 29696) { W = W2; DIN = 256; CTN = 8;  sl = s - 25600; }
    else if (s < 31744) { W = W3; DIN = 128; CTN = 8;  sl = s - 29696; }
    else if (s < 33792) { W = W4; DIN = 128; CTN = 8;  sl = s - 31744; }
    else                { W = W5; DIN = 128; CTN = 2;  sl = s - 33792; }
    int kt = sl / (CTN * 64);
    int ct = (sl / 64) % CTN;
    int ln = sl & 63;
    int r  = ct * 16 + (ln & 15);
    int k0 = kt * 32 + (ln >> 4) * 8;
    unsigned short v[8];
    #pragma unroll
    for (int j = 0; j < 8; j++) {
        int k = k0 + j;
        v[j] = (k < DIN) ? f2bf_bits(W[(size_t)r * DIN + k]) : (unsigned short)0;
    }
    uint4 pk;
    pk.x = (unsigned)v[0] | ((unsigned)v[1] << 16);
    pk.y = (unsigned)v[2] | ((unsigned)v[3] << 16);
    pk.z = (unsigned)v[4] | ((unsigned)v[5] << 16);
    pk.w = (unsigned)v[6] | ((unsigned)v[7] << 16);
    *(uint4*)(out + (size_t)s * 8) = pk;
}

// ---------------------------------------------------------------------------
// Layer 6: out = log_softmax(relu(X @ W6^T + b6)); X bf16 [B,32], one thr/row.
// Block 0 also writes the 5 entropy means (H complete: L5 precedes in-stream).
// ---------------------------------------------------------------------------
__global__ __launch_bounds__(256) void layer6_kernel(
    const unsigned short* __restrict__ Xb, const float* __restrict__ W,
    const float* __restrict__ b, float* __restrict__ out,
    const float* __restrict__ Hacc, float* __restrict__ out_tail)
{
    __shared__ float Wl[320];
    __shared__ float bl[10];
    const int t = threadIdx.x;
    for (int i = t; i < 320; i += 256) Wl[i] = W[i];
    if (t < 10) bl[t] = b[t];
    if (blockIdx.x == 0 && t < 5) out_tail[t] = Hacc[t] * (1.0f / 65536.0f);
    __syncthreads();

    const size_t row = (size_t)blockIdx.x * 256 + t;
    float x[32];
    const uint4* xp = (const uint4*)(Xb + row * 32);
    #pragma unroll
    for (int i = 0; i < 4; i++) {
        uint4 v = xp[i];
        unsigned u[4] = {v.x, v.y, v.z, v.w};
        #pragma unroll
        for (int j = 0; j < 4; j++) {
            x[8 * i + 2 * j]     = bf2f((unsigned short)(u[j] & 0xffffu));
            x[8 * i + 2 * j + 1] = bf2f((unsigned short)(u[j] >> 16));
        }
    }

    float z[10];
    float m = -1e30f;
    #pragma unroll
    for (int j = 0; j < 10; j++) {
        float s = bl[j];
        #pragma unroll
        for (int k = 0; k < 32; k++) s = fmaf(x[k], Wl[j * 32 + k], s);
        z[j] = fmaxf(s, 0.0f);
        m = fmaxf(m, z[j]);
    }
    float se = 0.0f;
    #pragma unroll
    for (int j = 0; j < 10; j++) se += __expf(z[j] - m);
    float ls = __logf(se);
    float* op = out + row * 10;
    #pragma unroll
    for (int j = 0; j < 10; j++) op[j] = z[j] - m - ls;
}

// ---------------------------------------------------------------------------
extern "C" void kernel_launch(void* const* d_in, const int* in_sizes, int n_in,
                              void* d_out, int out_size, void* d_ws, size_t ws_size,
                              hipStream_t stream)
{
    const float* x  = (const float*)d_in[0];
    const float* W1 = (const float*)d_in[1];  const float* b1 = (const float*)d_in[2];
    const float* W2 = (const float*)d_in[3];  const float* b2 = (const float*)d_in[4];
    const float* W3 = (const float*)d_in[5];  const float* b3 = (const float*)d_in[6];
    const float* W4 = (const float*)d_in[7];  const float* b4 = (const float*)d_in[8];
    const float* W5 = (const float*)d_in[9];  const float* b5 = (const float*)d_in[10];
    const float* W6 = (const float*)d_in[11]; const float* b6 = (const float*)d_in[12];
    float* out = (float*)d_out;

    constexpr int B = 65536;
    char* ws = (char*)d_ws;
    float* H = (float*)ws;                               // 5 floats @ 0
    unsigned short* Wfrag = (unsigned short*)(ws + 256); // 34304 slots * 16 B
    unsigned short* W1f = Wfrag;                         // 25600 slots
    unsigned short* W2f = W1f + 25600 * 8;
    unsigned short* W3f = W2f + 4096 * 8;
    unsigned short* W4f = W3f + 2048 * 8;
    unsigned short* W5f = W4f + 2048 * 8;
    unsigned short* bufA = (unsigned short*)(ws + (1 << 20));                    // B*256 bf16
    unsigned short* bufB = (unsigned short*)(ws + (1 << 20) + (size_t)B * 512);  // B*128 bf16

    hipMemsetAsync(H, 0, 5 * sizeof(float), stream);
    convert_wfrag<<<134, 256, 0, stream>>>(W1, W2, W3, W4, W5, Wfrag);

    layer_mfma<784, 256, true , 2><<<B / 128, 256, 0, stream>>>(x,    W1f, b1, bufA, H + 0);
    layer_mfma<256, 128, false, 1><<<B /  64, 256, 0, stream>>>(bufA, W2f, b2, bufB, H + 1);
    layer_mfma<128, 128, false, 1><<<B /  64, 256, 0, stream>>>(bufB, W3f, b3, bufA, H + 2);
    layer_mfma<128, 128, false, 1><<<B /  64, 256, 0, stream>>>(bufA, W4f, b4, bufB, H + 3);
    layer_mfma<128,  32, false, 1><<<B /  64, 256, 0, stream>>>(bufB, W5f, b5, bufA, H + 4);

    layer6_kernel<<<B / 256, 256, 0, stream>>>(bufA, W6, b6, out, H, out + (size_t)B * 10);
}

// Round 6
// 620.012 us; speedup vs baseline: 1.1251x; 1.1251x over previous
//
#include <hip/hip_runtime.h>
#include <hip/hip_bf16.h>
#include <math.h>

#define ALPHA 0.01f

typedef __bf16 bf16x8 __attribute__((ext_vector_type(8)));
typedef float  floatx4 __attribute__((ext_vector_type(4)));

static __device__ __forceinline__ unsigned short f2bf_bits(float f) {
    return __builtin_bit_cast(unsigned short, (__bf16)f);   // RNE
}
static __device__ __forceinline__ float bf2f(unsigned short u) {
    return __builtin_bit_cast(float, (unsigned)u << 16);    // exact
}

// async global->LDS, 16 B per lane, zero destination VGPRs.
// HW: lds dest = wave-uniform base + lane*16 (no per-lane scatter).
static __device__ __forceinline__ void glds16(const void* g, void* l) {
    __builtin_amdgcn_global_load_lds(
        (const __attribute__((address_space(1))) unsigned int*)g,
        (__attribute__((address_space(3))) unsigned int*)l, 16, 0, 0);
}

// 16-lane (DPP row) reductions — pure VALU, no LDS traffic.
template <int CTRL>
static __device__ __forceinline__ float dppmov(float x) {
    int r = __builtin_amdgcn_update_dpp(0, __builtin_bit_cast(int, x), CTRL, 0xf, 0xf, false);
    return __builtin_bit_cast(float, r);
}
static __device__ __forceinline__ float red16min(float x) {
    x = fminf(x, dppmov<0x121>(x)); x = fminf(x, dppmov<0x122>(x));
    x = fminf(x, dppmov<0x124>(x)); x = fminf(x, dppmov<0x128>(x));
    return x;
}
static __device__ __forceinline__ float red16max(float x) {
    x = fmaxf(x, dppmov<0x121>(x)); x = fmaxf(x, dppmov<0x122>(x));
    x = fmaxf(x, dppmov<0x124>(x)); x = fmaxf(x, dppmov<0x128>(x));
    return x;
}
static __device__ __forceinline__ float red16sum(float x) {
    x += dppmov<0x121>(x); x += dppmov<0x122>(x);
    x += dppmov<0x124>(x); x += dppmov<0x128>(x);
    return x;
}

// ---------------------------------------------------------------------------
// MFMA layer, m97-style 2-barrier K-loop with global_load_lds staging:
// Y(bf16) = leaky_relu(X @ W^T + b) + per-row histogram entropy -> *Hacc.
//
// Block = 256 thr (4 waves) x 64 rows x full DOUT; wave w owns rows
// [w*16, w*16+16), AF=1, CTN = DOUT/16 accumulators.
// X tile [64][32] staged via glds16; global side XOR-swizzled so the
// A-frag ds_read_b128s spread 2-way-free across banks.
// W tile staged from fragment-major global layout (slot (kt*CTN+ct)*64+lane)
// -> staging is lane-linear; B-frag read = bufW + (ct*64+lane)*16 (contig).
// fp32->bf16 (L1) converts at frag-read time, 12 VALU/ktile.
// Entropy: register-resident per quad, DPP reductions, packed-u16 LDS
// histogram with bank-spread word mapping (R4-proven).
// ---------------------------------------------------------------------------
template <int DIN, int DOUT, bool XF32, int MINB>
__global__ __launch_bounds__(256, MINB) void layer_mfma(
    const void* __restrict__ Xin, const unsigned short* __restrict__ Wf,
    const float* __restrict__ bias, unsigned short* __restrict__ Y,
    float* __restrict__ Hacc)
{
    constexpr int CTN     = DOUT / 16;
    constexpr int KT_FULL = DIN / 32;
    constexpr int TAIL    = DIN % 32;            // L1: 16, others 0
    constexpr int HALF    = DOUT / 2;
    constexpr int LOG2D   = (DOUT == 256) ? 8 : (DOUT == 128) ? 7 : 5;
    constexpr float LOGB  = (DOUT == 256) ? 5.54517744f
                          : (DOUT == 128) ? 4.85203026f : 3.46573590f;
    constexpr int XBYTES  = 64 * 32 * (XF32 ? 4 : 2);
    constexpr int WBYTES  = DOUT * 64;
    static_assert(DOUT % 32 == 0 && DOUT <= 256, "DOUT");
    static_assert(XF32 || TAIL == 0, "bf16 input requires DIN%32==0");

    __shared__ __align__(16) char smemX[XBYTES];
    __shared__ __align__(16) char smemW[WBYTES];
    __shared__ unsigned int counts[16][HALF + 1];

    const int t      = threadIdx.x;
    const int lane   = t & 63;
    const int lane16 = lane & 15;
    const int q      = lane >> 4;
    const int w      = t >> 6;
    const int row0   = blockIdx.x * 64;
    const int myrow  = w * 16 + lane16;          // this lane's A row in tile

    float biasr[CTN];
    #pragma unroll
    for (int ct = 0; ct < CTN; ct++) biasr[ct] = bias[ct * 16 + lane16];

    floatx4 acc[CTN];
    #pragma unroll
    for (int ct = 0; ct < CTN; ct++) acc[ct] = (floatx4)(0.0f);

    // ---- staging (global_load_lds; zero dest VGPRs) ----
    auto stageW = [&](int kt) {
        #pragma unroll
        for (int j = w; j < CTN; j += 4)
            glds16(Wf + ((size_t)kt * CTN * 64 + j * 64 + lane) * 8,
                   smemW + j * 64 * 16);
    };
    auto stageX = [&](int kt) {
        if constexpr (XF32) {
            const float* X = (const float*)Xin;
            #pragma unroll
            for (int j = 0; j < 2; j++) {
                int s  = w * 128 + j * 64 + lane;       // lds slot (linear)
                int gc = (s & ~7) | ((s ^ (s >> 3)) & 7); // global chunk (swz)
                int r  = gc >> 3, c = gc & 7;
                glds16(X + (size_t)(row0 + r) * DIN + kt * 32 + c * 4,
                       smemX + (w * 128 + j * 64) * 16);
            }
        } else {
            const unsigned short* X = (const unsigned short*)Xin;
            int s  = w * 64 + lane;
            int gc = (s & ~3) | ((s ^ (s >> 2)) & 3);
            int r  = gc >> 2, c = gc & 3;
            glds16(X + (size_t)(row0 + r) * DIN + kt * 32 + c * 8,
                   smemX + (w * 64) * 16);
        }
    };

    // ---- compute one staged 32-wide k-tile ----
    auto compute = [&]() {
        bf16x8 a;
        if constexpr (XF32) {
            int s0 = myrow * 8 + (((2 * q)     ^ myrow) & 7);
            int s1 = myrow * 8 + (((2 * q + 1) ^ myrow) & 7);
            float4 f0 = *(const float4*)(smemX + s0 * 16);
            float4 f1 = *(const float4*)(smemX + s1 * 16);
            uint4 pk;
            pk.x = (unsigned)f2bf_bits(f0.x) | ((unsigned)f2bf_bits(f0.y) << 16);
            pk.y = (unsigned)f2bf_bits(f0.z) | ((unsigned)f2bf_bits(f0.w) << 16);
            pk.z = (unsigned)f2bf_bits(f1.x) | ((unsigned)f2bf_bits(f1.y) << 16);
            pk.w = (unsigned)f2bf_bits(f1.z) | ((unsigned)f2bf_bits(f1.w) << 16);
            a = __builtin_bit_cast(bf16x8, pk);
        } else {
            int s = myrow * 4 + ((q ^ myrow) & 3);
            a = *(const bf16x8*)(smemX + s * 16);
        }
        #pragma unroll
        for (int ct = 0; ct < CTN; ct++) {
            bf16x8 bw = *(const bf16x8*)(smemW + (ct * 64 + lane) * 16);
            acc[ct] = __builtin_amdgcn_mfma_f32_16x16x32_bf16(a, bw, acc[ct], 0, 0, 0);
        }
    };

    #pragma unroll 1
    for (int kt = 0; kt < KT_FULL; kt++) {
        __syncthreads();         // previous tile fully consumed
        stageX(kt);
        stageW(kt);
        __syncthreads();         // drains vmcnt -> staged data visible
        compute();
    }

    if constexpr (TAIL > 0) {    // L1: k = 768..784, W-frag buffer zero-padded
        __syncthreads();
        stageW(KT_FULL);
        {
            const float* X = (const float*)Xin;
            int r = t >> 2, c = t & 3;           // valid chunk cols 0..3
            float4 v = *(const float4*)(X + (size_t)(row0 + r) * DIN
                                        + KT_FULL * 32 + c * 4);
            *(float4*)(smemX + (r * 8 + ((c ^ r) & 7)) * 16) = v;
            int c2 = c + 4;                       // zero chunk cols 4..7
            *(float4*)(smemX + (r * 8 + ((c2 ^ r) & 7)) * 16)
                = make_float4(0.f, 0.f, 0.f, 0.f);
        }
        __syncthreads();
        compute();
    }

    // ---- epilogue: bias + leaky_relu in registers; direct bf16 stores
    #pragma unroll
    for (int ct = 0; ct < CTN; ct++) {
        #pragma unroll
        for (int reg = 0; reg < 4; reg++) {
            float v = acc[ct][reg] + biasr[ct];
            v = v > 0.0f ? v : ALPHA * v;
            acc[ct][reg] = v;
            Y[(size_t)(row0 + w * 16 + q * 4 + reg) * DOUT
              + ct * 16 + lane16] = f2bf_bits(v);
        }
    }

    // ---- entropy: quad q owns rows q*4 + reg (4 rows in parallel)
    unsigned int* cc = counts[w * 4 + q];
    float Hq = 0.0f;
    #pragma unroll
    for (int reg = 0; reg < 4; reg++) {
        float mn = acc[0][reg], mx = mn;
        #pragma unroll
        for (int ct = 1; ct < CTN; ct++) {
            mn = fminf(mn, acc[ct][reg]);
            mx = fmaxf(mx, acc[ct][reg]);
        }
        mn = red16min(mn);
        mx = red16max(mx);
        float wdt = mx - mn;
        float scale = (float)DOUT / (wdt > 0.0f ? wdt : 1.0f);

        #pragma unroll
        for (int i = 0; i < DOUT / 32; i++) cc[lane16 + 16 * i] = 0u;
        // in-wave DS program order: zeros -> atomics -> reads

        #pragma unroll
        for (int ct = 0; ct < CTN; ct++) {
            int b = (int)((acc[ct][reg] - mn) * scale);
            b = b < (DOUT - 1) ? b : (DOUT - 1);
            atomicAdd(&cc[b & (HALF - 1)],
                      1u << (((b >> (LOG2D - 1)) & 1) << 4));
        }

        float s = 0.0f;
        #pragma unroll
        for (int i = 0; i < DOUT / 32; i++) {
            unsigned int word = cc[lane16 + 16 * i];
            int c0 = (int)(word & 0xffffu), c1 = (int)(word >> 16);
            if (c0 > 0) { float p = (float)c0 * (1.0f / (float)DOUT); s += p * __logf(p); }
            if (c1 > 0) { float p = (float)c1 * (1.0f / (float)DOUT); s += p * __logf(p); }
        }
        s = red16sum(s);
        Hq += LOGB - s;
    }
    Hq += __shfl_xor(Hq, 16, 64);
    Hq += __shfl_xor(Hq, 32, 64);
    if (lane == 0) atomicAdd(Hacc, Hq);
}

// ---------------------------------------------------------------------------
// fp32 W1..W5 -> bf16 fragment-major slots, concatenated into ws.
// Slot s_local = (kt*CTN + ct)*64 + lane holds
// W[ct*16 + (lane&15)][kt*32 + (lane>>4)*8 .. +8), zero-padded past DIN.
// ---------------------------------------------------------------------------
__global__ void convert_wfrag(const float* __restrict__ W1, const float* __restrict__ W2,
                              const float* __restrict__ W3, const float* __restrict__ W4,
                              const float* __restrict__ W5, unsigned short* __restrict__ out)
{
    // slots: L1 25*16*64=25600 | L2 8*8*64=4096 | L3 4*8*64=2048 | L4 2048 | L5 4*2*64=512
    int s = blockIdx.x * 256 + threadIdx.x;
    if (s >= 34304) return;
    const float* W; int DIN, CTN, sl;
    if      (s < 25600) { W = W1; DIN = 784; CTN = 16; sl = s;         }
    else if (s < 29696) { W = W2; DIN = 256; CTN = 8;  sl = s - 25600; }
    else if (s < 31744) { W = W3; DIN = 128; CTN = 8;  sl = s - 29696; }
    else if (s < 33792) { W = W4; DIN = 128; CTN = 8;  sl = s - 31744; }
    else                { W = W5; DIN = 128; CTN = 2;  sl = s - 33792; }
    int kt = sl / (CTN * 64);
    int ct = (sl / 64) % CTN;
    int ln = sl & 63;
    int r  = ct * 16 + (ln & 15);
    int k0 = kt * 32 + (ln >> 4) * 8;
    unsigned short v[8];
    #pragma unroll
    for (int j = 0; j < 8; j++) {
        int k = k0 + j;
        v[j] = (k < DIN) ? f2bf_bits(W[(size_t)r * DIN + k]) : (unsigned short)0;
    }
    uint4 pk;
    pk.x = (unsigned)v[0] | ((unsigned)v[1] << 16);
    pk.y = (unsigned)v[2] | ((unsigned)v[3] << 16);
    pk.z = (unsigned)v[4] | ((unsigned)v[5] << 16);
    pk.w = (unsigned)v[6] | ((unsigned)v[7] << 16);
    *(uint4*)(out + (size_t)s * 8) = pk;
}

// ---------------------------------------------------------------------------
// Layer 6: out = log_softmax(relu(X @ W6^T + b6)); X bf16 [B,32], one thr/row.
// Block 0 also writes the 5 entropy means (H complete: L5 precedes in-stream).
// ---------------------------------------------------------------------------
__global__ __launch_bounds__(256) void layer6_kernel(
    const unsigned short* __restrict__ Xb, const float* __restrict__ W,
    const float* __restrict__ b, float* __restrict__ out,
    const float* __restrict__ Hacc, float* __restrict__ out_tail)
{
    __shared__ float Wl[320];
    __shared__ float bl[10];
    const int t = threadIdx.x;
    for (int i = t; i < 320; i += 256) Wl[i] = W[i];
    if (t < 10) bl[t] = b[t];
    if (blockIdx.x == 0 && t < 5) out_tail[t] = Hacc[t] * (1.0f / 65536.0f);
    __syncthreads();

    const size_t row = (size_t)blockIdx.x * 256 + t;
    float x[32];
    const uint4* xp = (const uint4*)(Xb + row * 32);
    #pragma unroll
    for (int i = 0; i < 4; i++) {
        uint4 v = xp[i];
        unsigned u[4] = {v.x, v.y, v.z, v.w};
        #pragma unroll
        for (int j = 0; j < 4; j++) {
            x[8 * i + 2 * j]     = bf2f((unsigned short)(u[j] & 0xffffu));
            x[8 * i + 2 * j + 1] = bf2f((unsigned short)(u[j] >> 16));
        }
    }

    float z[10];
    float m = -1e30f;
    #pragma unroll
    for (int j = 0; j < 10; j++) {
        float s = bl[j];
        #pragma unroll
        for (int k = 0; k < 32; k++) s = fmaf(x[k], Wl[j * 32 + k], s);
        z[j] = fmaxf(s, 0.0f);
        m = fmaxf(m, z[j]);
    }
    float se = 0.0f;
    #pragma unroll
    for (int j = 0; j < 10; j++) se += __expf(z[j] - m);
    float ls = __logf(se);
    float* op = out + row * 10;
    #pragma unroll
    for (int j = 0; j < 10; j++) op[j] = z[j] - m - ls;
}

// ---------------------------------------------------------------------------
extern "C" void kernel_launch(void* const* d_in, const int* in_sizes, int n_in,
                              void* d_out, int out_size, void* d_ws, size_t ws_size,
                              hipStream_t stream)
{
    const float* x  = (const float*)d_in[0];
    const float* W1 = (const float*)d_in[1];  const float* b1 = (const float*)d_in[2];
    const float* W2 = (const float*)d_in[3];  const float* b2 = (const float*)d_in[4];
    const float* W3 = (const float*)d_in[5];  const float* b3 = (const float*)d_in[6];
    const float* W4 = (const float*)d_in[7];  const float* b4 = (const float*)d_in[8];
    const float* W5 = (const float*)d_in[9];  const float* b5 = (const float*)d_in[10];
    const float* W6 = (const float*)d_in[11]; const float* b6 = (const float*)d_in[12];
    float* out = (float*)d_out;

    constexpr int B = 65536;
    char* ws = (char*)d_ws;
    float* H = (float*)ws;                               // 5 floats @ 0
    unsigned short* Wfrag = (unsigned short*)(ws + 256); // 34304 slots * 16 B
    unsigned short* W1f = Wfrag;                         // 25600 slots
    unsigned short* W2f = W1f + 25600 * 8;
    unsigned short* W3f = W2f + 4096 * 8;
    unsigned short* W4f = W3f + 2048 * 8;
    unsigned short* W5f = W4f + 2048 * 8;
    unsigned short* bufA = (unsigned short*)(ws + (1 << 20));                    // B*256 bf16
    unsigned short* bufB = (unsigned short*)(ws + (1 << 20) + (size_t)B * 512);  // B*128 bf16

    hipMemsetAsync(H, 0, 5 * sizeof(float), stream);
    convert_wfrag<<<134, 256, 0, stream>>>(W1, W2, W3, W4, W5, Wfrag);

    layer_mfma<784, 256, true , 3><<<B / 64, 256, 0, stream>>>(x,    W1f, b1, bufA, H + 0);
    layer_mfma<256, 128, false, 4><<<B / 64, 256, 0, stream>>>(bufA, W2f, b2, bufB, H + 1);
    layer_mfma<128, 128, false, 4><<<B / 64, 256, 0, stream>>>(bufB, W3f, b3, bufA, H + 2);
    layer_mfma<128, 128, false, 4><<<B / 64, 256, 0, stream>>>(bufA, W4f, b4, bufB, H + 3);
    layer_mfma<128,  32, false, 4><<<B / 64, 256, 0, stream>>>(bufB, W5f, b5, bufA, H + 4);

    layer6_kernel<<<B / 256, 256, 0, stream>>>(bufA, W6, b6, out, H, out + (size_t)B * 10);
}

// Round 7
// 409.760 us; speedup vs baseline: 1.7024x; 1.5131x over previous
//
#include <hip/hip_runtime.h>
#include <hip/hip_bf16.h>
#include <math.h>

#define ALPHA 0.01f

typedef __bf16 bf16x8 __attribute__((ext_vector_type(8)));
typedef float  floatx4 __attribute__((ext_vector_type(4)));

static __device__ __forceinline__ unsigned short f2bf_bits(float f) {
    return __builtin_bit_cast(unsigned short, (__bf16)f);   // RNE
}
static __device__ __forceinline__ float bf2f(unsigned short u) {
    return __builtin_bit_cast(float, (unsigned)u << 16);    // exact
}

// async global->LDS, 16 B per lane, zero destination VGPRs.
static __device__ __forceinline__ void glds16(const void* g, void* l) {
    __builtin_amdgcn_global_load_lds(
        (const __attribute__((address_space(1))) unsigned int*)g,
        (__attribute__((address_space(3))) unsigned int*)l, 16, 0, 0);
}

// 16-lane (DPP row) reductions — pure VALU, no LDS traffic.
template <int CTRL>
static __device__ __forceinline__ float dppmov(float x) {
    int r = __builtin_amdgcn_update_dpp(0, __builtin_bit_cast(int, x), CTRL, 0xf, 0xf, false);
    return __builtin_bit_cast(float, r);
}
static __device__ __forceinline__ float red16min(float x) {
    x = fminf(x, dppmov<0x121>(x)); x = fminf(x, dppmov<0x122>(x));
    x = fminf(x, dppmov<0x124>(x)); x = fminf(x, dppmov<0x128>(x));
    return x;
}
static __device__ __forceinline__ float red16max(float x) {
    x = fmaxf(x, dppmov<0x121>(x)); x = fmaxf(x, dppmov<0x122>(x));
    x = fmaxf(x, dppmov<0x124>(x)); x = fmaxf(x, dppmov<0x128>(x));
    return x;
}
static __device__ __forceinline__ float red16sum(float x) {
    x += dppmov<0x121>(x); x += dppmov<0x122>(x);
    x += dppmov<0x124>(x); x += dppmov<0x128>(x);
    return x;
}

// ---------------------------------------------------------------------------
// MFMA layer: Y(bf16) = leaky_relu(X @ W^T + b) + per-row histogram entropy.
// Per-block entropy partial is PLAIN-STORED to Hpart[blockIdx] (no global
// atomics — 1024 same-address device atomics was a ~100 µs serial tail/layer).
//
// WRES=true (L2..L5): whole W (fragment-major) staged to LDS ONCE via glds,
//   one barrier, then a BARRIER-FREE K-loop: A-frags register-prefetched
//   per-lane from global (L2-resident X), B-frags = conflict-free
//   contiguous LDS reads. Wave w owns rows [w*16, w*16+16).
// WRES=false (L1): R6 structure — per-ktile glds staging of X(+swizzle)
//   and W-chunk, 2-barrier K-loop; fp32->bf16 conversion at frag-read.
// ---------------------------------------------------------------------------
template <int DIN, int DOUT, bool XF32, bool WRES, int MINB>
__global__ __launch_bounds__(256, MINB) void layer_mfma(
    const void* __restrict__ Xin, const unsigned short* __restrict__ Wf,
    const float* __restrict__ bias, unsigned short* __restrict__ Y,
    float* __restrict__ Hpart)
{
    constexpr int CTN     = DOUT / 16;
    constexpr int KT_FULL = DIN / 32;
    constexpr int TAIL    = DIN % 32;            // L1: 16, others 0
    constexpr int HALF    = DOUT / 2;
    constexpr int LOG2D   = (DOUT == 256) ? 8 : (DOUT == 128) ? 7 : 5;
    constexpr float LOGB  = (DOUT == 256) ? 5.54517744f
                          : (DOUT == 128) ? 4.85203026f : 3.46573590f;
    constexpr int XBYTES  = WRES ? 16 : 64 * 32 * (XF32 ? 4 : 2);
    constexpr int WBYTES  = WRES ? (size_t)DIN * DOUT * 2 : DOUT * 64;
    constexpr int WSLOTS  = (DIN / 32) * CTN * 64;   // 16B frag slots (WRES)
    static_assert(DOUT % 32 == 0 && DOUT <= 256, "DOUT");
    static_assert(XF32 || TAIL == 0, "bf16 input requires DIN%32==0");

    __shared__ __align__(16) char smemX[XBYTES];
    __shared__ __align__(16) char smemW[WBYTES];
    __shared__ unsigned int counts[16][HALF + 1];
    __shared__ float hsum[4];

    const int t      = threadIdx.x;
    const int lane   = t & 63;
    const int lane16 = lane & 15;
    const int q      = lane >> 4;
    const int w      = t >> 6;
    const int row0   = blockIdx.x * 64;
    const int myrow  = w * 16 + lane16;          // lane's A row in tile

    float biasr[CTN];
    #pragma unroll
    for (int ct = 0; ct < CTN; ct++) biasr[ct] = bias[ct * 16 + lane16];

    floatx4 acc[CTN];
    #pragma unroll
    for (int ct = 0; ct < CTN; ct++) acc[ct] = (floatx4)(0.0f);

    if constexpr (WRES) {
        // ---- stage ALL of W into LDS once (thread-linear slots) ----
        static_assert(WSLOTS % 256 == 0, "WSLOTS");
        #pragma unroll
        for (int i = 0; i < WSLOTS / 256; i++)
            glds16(Wf + ((size_t)(i * 256 + w * 64 + lane)) * 8,
                   smemW + (i * 256 + w * 64) * 16);
        __syncthreads();

        // ---- barrier-free K-loop: register-prefetched A, LDS B ----
        const unsigned short* X = (const unsigned short*)Xin;
        const size_t abase = (size_t)(row0 + myrow) * DIN + q * 8;
        bf16x8 acur = *(const bf16x8*)(X + abase);
        #pragma unroll
        for (int kt = 0; kt < KT_FULL; kt++) {
            bf16x8 anxt = acur;
            if (kt + 1 < KT_FULL)
                anxt = *(const bf16x8*)(X + abase + (kt + 1) * 32);
            #pragma unroll
            for (int ct = 0; ct < CTN; ct++) {
                bf16x8 bw = *(const bf16x8*)(smemW + ((kt * CTN + ct) * 64 + lane) * 16);
                acc[ct] = __builtin_amdgcn_mfma_f32_16x16x32_bf16(acur, bw, acc[ct], 0, 0, 0);
            }
            acur = anxt;
        }
    } else {
        // ---- R6 path: per-ktile glds staging, 2-barrier K-loop ----
        auto stageW = [&](int kt) {
            #pragma unroll
            for (int j = w; j < CTN; j += 4)
                glds16(Wf + ((size_t)kt * CTN * 64 + j * 64 + lane) * 8,
                       smemW + j * 64 * 16);
        };
        auto stageX = [&](int kt) {
            const float* X = (const float*)Xin;
            #pragma unroll
            for (int j = 0; j < 2; j++) {
                int s  = w * 128 + j * 64 + lane;         // lds slot (linear)
                int gc = (s & ~7) | ((s ^ (s >> 3)) & 7); // global chunk (swz)
                int r  = gc >> 3, c = gc & 7;
                glds16(X + (size_t)(row0 + r) * DIN + kt * 32 + c * 4,
                       smemX + (w * 128 + j * 64) * 16);
            }
        };
        auto compute = [&]() {
            int s0 = myrow * 8 + (((2 * q)     ^ myrow) & 7);
            int s1 = myrow * 8 + (((2 * q + 1) ^ myrow) & 7);
            float4 f0 = *(const float4*)(smemX + s0 * 16);
            float4 f1 = *(const float4*)(smemX + s1 * 16);
            uint4 pk;
            pk.x = (unsigned)f2bf_bits(f0.x) | ((unsigned)f2bf_bits(f0.y) << 16);
            pk.y = (unsigned)f2bf_bits(f0.z) | ((unsigned)f2bf_bits(f0.w) << 16);
            pk.z = (unsigned)f2bf_bits(f1.x) | ((unsigned)f2bf_bits(f1.y) << 16);
            pk.w = (unsigned)f2bf_bits(f1.z) | ((unsigned)f2bf_bits(f1.w) << 16);
            bf16x8 a = __builtin_bit_cast(bf16x8, pk);
            #pragma unroll
            for (int ct = 0; ct < CTN; ct++) {
                bf16x8 bw = *(const bf16x8*)(smemW + (ct * 64 + lane) * 16);
                acc[ct] = __builtin_amdgcn_mfma_f32_16x16x32_bf16(a, bw, acc[ct], 0, 0, 0);
            }
        };

        #pragma unroll 1
        for (int kt = 0; kt < KT_FULL; kt++) {
            __syncthreads();
            stageX(kt);
            stageW(kt);
            __syncthreads();
            compute();
        }
        if constexpr (TAIL > 0) {   // L1: k = 768..784 (W slots zero-padded)
            __syncthreads();
            stageW(KT_FULL);
            {
                const float* X = (const float*)Xin;
                int r = t >> 2, c = t & 3;
                float4 v = *(const float4*)(X + (size_t)(row0 + r) * DIN
                                            + KT_FULL * 32 + c * 4);
                *(float4*)(smemX + (r * 8 + ((c ^ r) & 7)) * 16) = v;
                int c2 = c + 4;
                *(float4*)(smemX + (r * 8 + ((c2 ^ r) & 7)) * 16)
                    = make_float4(0.f, 0.f, 0.f, 0.f);
            }
            __syncthreads();
            compute();
        }
    }

    // ---- epilogue: bias + leaky_relu in registers; direct bf16 stores ----
    #pragma unroll
    for (int ct = 0; ct < CTN; ct++) {
        #pragma unroll
        for (int reg = 0; reg < 4; reg++) {
            float v = acc[ct][reg] + biasr[ct];
            v = v > 0.0f ? v : ALPHA * v;
            acc[ct][reg] = v;
            Y[(size_t)(row0 + w * 16 + q * 4 + reg) * DOUT
              + ct * 16 + lane16] = f2bf_bits(v);
        }
    }

    // ---- entropy: quad q owns rows q*4 + reg (4 rows in parallel) ----
    unsigned int* cc = counts[w * 4 + q];
    float Hq = 0.0f;
    #pragma unroll
    for (int reg = 0; reg < 4; reg++) {
        float mn = acc[0][reg], mx = mn;
        #pragma unroll
        for (int ct = 1; ct < CTN; ct++) {
            mn = fminf(mn, acc[ct][reg]);
            mx = fmaxf(mx, acc[ct][reg]);
        }
        mn = red16min(mn);
        mx = red16max(mx);
        float wdt = mx - mn;
        float scale = (float)DOUT / (wdt > 0.0f ? wdt : 1.0f);

        #pragma unroll
        for (int i = 0; i < DOUT / 32; i++) cc[lane16 + 16 * i] = 0u;
        // in-wave DS program order: zeros -> atomics -> reads

        #pragma unroll
        for (int ct = 0; ct < CTN; ct++) {
            int b = (int)((acc[ct][reg] - mn) * scale);
            b = b < (DOUT - 1) ? b : (DOUT - 1);
            atomicAdd(&cc[b & (HALF - 1)],
                      1u << (((b >> (LOG2D - 1)) & 1) << 4));
        }

        float s = 0.0f;
        #pragma unroll
        for (int i = 0; i < DOUT / 32; i++) {
            unsigned int word = cc[lane16 + 16 * i];
            int c0 = (int)(word & 0xffffu), c1 = (int)(word >> 16);
            if (c0 > 0) { float p = (float)c0 * (1.0f / (float)DOUT); s += p * __logf(p); }
            if (c1 > 0) { float p = (float)c1 * (1.0f / (float)DOUT); s += p * __logf(p); }
        }
        s = red16sum(s);
        Hq += LOGB - s;
    }
    Hq += __shfl_xor(Hq, 16, 64);
    Hq += __shfl_xor(Hq, 32, 64);

    if (lane == 0) hsum[w] = Hq;
    __syncthreads();
    if (t == 0) Hpart[blockIdx.x] = hsum[0] + hsum[1] + hsum[2] + hsum[3];
}

// ---------------------------------------------------------------------------
// fp32 W1..W5 -> bf16 fragment-major slots, concatenated into ws.
// Slot s_local = (kt*CTN + ct)*64 + lane holds
// W[ct*16 + (lane&15)][kt*32 + (lane>>4)*8 .. +8), zero-padded past DIN.
// ---------------------------------------------------------------------------
__global__ void convert_wfrag(const float* __restrict__ W1, const float* __restrict__ W2,
                              const float* __restrict__ W3, const float* __restrict__ W4,
                              const float* __restrict__ W5, unsigned short* __restrict__ out)
{
    // slots: L1 25*16*64=25600 | L2 8*8*64=4096 | L3 4*8*64=2048 | L4 2048 | L5 4*2*64=512
    int s = blockIdx.x * 256 + threadIdx.x;
    if (s >= 34304) return;
    const float* W; int DIN, CTN, sl;
    if      (s < 25600) { W = W1; DIN = 784; CTN = 16; sl = s;         }
    else if (s < 29696) { W = W2; DIN = 256; CTN = 8;  sl = s - 25600; }
    else if (s < 31744) { W = W3; DIN = 128; CTN = 8;  sl = s - 29696; }
    else if (s < 33792) { W = W4; DIN = 128; CTN = 8;  sl = s - 31744; }
    else                { W = W5; DIN = 128; CTN = 2;  sl = s - 33792; }
    int kt = sl / (CTN * 64);
    int ct = (sl / 64) % CTN;
    int ln = sl & 63;
    int r  = ct * 16 + (ln & 15);
    int k0 = kt * 32 + (ln >> 4) * 8;
    unsigned short v[8];
    #pragma unroll
    for (int j = 0; j < 8; j++) {
        int k = k0 + j;
        v[j] = (k < DIN) ? f2bf_bits(W[(size_t)r * DIN + k]) : (unsigned short)0;
    }
    uint4 pk;
    pk.x = (unsigned)v[0] | ((unsigned)v[1] << 16);
    pk.y = (unsigned)v[2] | ((unsigned)v[3] << 16);
    pk.z = (unsigned)v[4] | ((unsigned)v[5] << 16);
    pk.w = (unsigned)v[6] | ((unsigned)v[7] << 16);
    *(uint4*)(out + (size_t)s * 8) = pk;
}

// ---------------------------------------------------------------------------
// Layer 6: out = log_softmax(relu(X @ W6^T + b6)); X bf16 [B,32], one thr/row.
// Block 0 reduces the 5x1024 entropy partials and writes the 5 means.
// ---------------------------------------------------------------------------
__global__ __launch_bounds__(256) void layer6_kernel(
    const unsigned short* __restrict__ Xb, const float* __restrict__ W,
    const float* __restrict__ b, float* __restrict__ out,
    const float* __restrict__ Hpart, float* __restrict__ out_tail)
{
    __shared__ float Wl[320];
    __shared__ float bl[10];
    __shared__ float hred[4][5];
    const int t = threadIdx.x;
    const int lane = t & 63;
    const int w = t >> 6;

    if (blockIdx.x == 0) {          // block-uniform branch: barrier is legal
        #pragma unroll
        for (int l = 0; l < 5; l++) {
            float s = Hpart[l * 1024 + t]       + Hpart[l * 1024 + t + 256]
                    + Hpart[l * 1024 + t + 512] + Hpart[l * 1024 + t + 768];
            #pragma unroll
            for (int off = 1; off <= 32; off <<= 1) s += __shfl_xor(s, off, 64);
            if (lane == 0) hred[w][l] = s;
        }
        __syncthreads();
        if (t < 5)
            out_tail[t] = (hred[0][t] + hred[1][t] + hred[2][t] + hred[3][t])
                          * (1.0f / 65536.0f);
    }

    for (int i = t; i < 320; i += 256) Wl[i] = W[i];
    if (t < 10) bl[t] = b[t];
    __syncthreads();

    const size_t row = (size_t)blockIdx.x * 256 + t;
    float x[32];
    const uint4* xp = (const uint4*)(Xb + row * 32);
    #pragma unroll
    for (int i = 0; i < 4; i++) {
        uint4 v = xp[i];
        unsigned u[4] = {v.x, v.y, v.z, v.w};
        #pragma unroll
        for (int j = 0; j < 4; j++) {
            x[8 * i + 2 * j]     = bf2f((unsigned short)(u[j] & 0xffffu));
            x[8 * i + 2 * j + 1] = bf2f((unsigned short)(u[j] >> 16));
        }
    }

    float z[10];
    float m = -1e30f;
    #pragma unroll
    for (int j = 0; j < 10; j++) {
        float s = bl[j];
        #pragma unroll
        for (int k = 0; k < 32; k++) s = fmaf(x[k], Wl[j * 32 + k], s);
        z[j] = fmaxf(s, 0.0f);
        m = fmaxf(m, z[j]);
    }
    float se = 0.0f;
    #pragma unroll
    for (int j = 0; j < 10; j++) se += __expf(z[j] - m);
    float ls = __logf(se);
    float* op = out + row * 10;
    #pragma unroll
    for (int j = 0; j < 10; j++) op[j] = z[j] - m - ls;
}

// ---------------------------------------------------------------------------
extern "C" void kernel_launch(void* const* d_in, const int* in_sizes, int n_in,
                              void* d_out, int out_size, void* d_ws, size_t ws_size,
                              hipStream_t stream)
{
    const float* x  = (const float*)d_in[0];
    const float* W1 = (const float*)d_in[1];  const float* b1 = (const float*)d_in[2];
    const float* W2 = (const float*)d_in[3];  const float* b2 = (const float*)d_in[4];
    const float* W3 = (const float*)d_in[5];  const float* b3 = (const float*)d_in[6];
    const float* W4 = (const float*)d_in[7];  const float* b4 = (const float*)d_in[8];
    const float* W5 = (const float*)d_in[9];  const float* b5 = (const float*)d_in[10];
    const float* W6 = (const float*)d_in[11]; const float* b6 = (const float*)d_in[12];
    float* out = (float*)d_out;

    constexpr int B = 65536;
    char* ws = (char*)d_ws;
    float* Hpart = (float*)ws;                             // 5*1024 floats
    unsigned short* Wfrag = (unsigned short*)(ws + 20480); // 34304 slots * 16 B
    unsigned short* W1f = Wfrag;                           // 25600 slots
    unsigned short* W2f = W1f + 25600 * 8;
    unsigned short* W3f = W2f + 4096 * 8;
    unsigned short* W4f = W3f + 2048 * 8;
    unsigned short* W5f = W4f + 2048 * 8;
    unsigned short* bufA = (unsigned short*)(ws + (1 << 20));                    // B*256 bf16
    unsigned short* bufB = (unsigned short*)(ws + (1 << 20) + (size_t)B * 512);  // B*128 bf16

    convert_wfrag<<<134, 256, 0, stream>>>(W1, W2, W3, W4, W5, Wfrag);

    layer_mfma<784, 256, true , false, 4><<<B / 64, 256, 0, stream>>>(x,    W1f, b1, bufA, Hpart + 0 * 1024);
    layer_mfma<256, 128, false, true , 2><<<B / 64, 256, 0, stream>>>(bufA, W2f, b2, bufB, Hpart + 1 * 1024);
    layer_mfma<128, 128, false, true , 4><<<B / 64, 256, 0, stream>>>(bufB, W3f, b3, bufA, Hpart + 2 * 1024);
    layer_mfma<128, 128, false, true , 4><<<B / 64, 256, 0, stream>>>(bufA, W4f, b4, bufB, Hpart + 3 * 1024);
    layer_mfma<128,  32, false, true , 4><<<B / 64, 256, 0, stream>>>(bufB, W5f, b5, bufA, Hpart + 4 * 1024);

    layer6_kernel<<<B / 256, 256, 0, stream>>>(bufA, W6, b6, out, Hpart, out + (size_t)B * 10);
}